// Round 7
// baseline (287.520 us; speedup 1.0000x reference)
//
#include <hip/hip_runtime.h>
#include <math.h>

// Problem constants
#define EMBED   1024
#define NHEADS  16
#define HD      64
#define BATCH   4
#define SEQ     2048
#define MROWS   (BATCH*SEQ)          // 8192
#define NKV     8388608ull           // B*H*N*64 elements per K/Q/V buffer

typedef short short8 __attribute__((ext_vector_type(8)));
typedef float floatx4 __attribute__((ext_vector_type(4)));
typedef float floatx16 __attribute__((ext_vector_type(16)));

union Frag8 { int4 i; short8 s; };

__device__ __forceinline__ unsigned short f2b(float f) {
    union { float f; unsigned u; } v; v.f = f;
    unsigned r = v.u + 0x7FFFu + ((v.u >> 16) & 1u);   // RN-even bf16
    return (unsigned short)(r >> 16);
}
__device__ __forceinline__ unsigned short f2b_fast(float f) {
    union { float f; unsigned u; } v; v.f = f;
    return (unsigned short)((v.u + 0x8000u) >> 16);    // round-half-up (2 ops)
}

// async global->LDS, 16B per lane; LDS dest = wave-uniform base + lane*16
#define GLDS16(gp, lp) __builtin_amdgcn_global_load_lds( \
    (const __attribute__((address_space(1))) unsigned int*)(gp), \
    (__attribute__((address_space(3))) unsigned int*)(lp), 16, 0, 0)

// ---------------------------------------------------------------------------
// Pre-pass: x fp32 -> bf16
// ---------------------------------------------------------------------------
__global__ __launch_bounds__(256) void convert_x(
    const float* __restrict__ x, unsigned short* __restrict__ x16)
{
    size_t idx = ((size_t)blockIdx.x * 256 + threadIdx.x) * 8;
    float4 a = *(const float4*)(x + idx);
    float4 b = *(const float4*)(x + idx + 4);
    ushort4 u0, u1;
    u0.x = f2b(a.x); u0.y = f2b(a.y); u0.z = f2b(a.z); u0.w = f2b(a.w);
    u1.x = f2b(b.x); u1.y = f2b(b.y); u1.z = f2b(b.z); u1.w = f2b(b.w);
    *(ushort4*)(x16 + idx) = u0;
    *(ushort4*)(x16 + idx + 4) = u1;
}

// ---------------------------------------------------------------------------
// Pre-pass: W_kqv [16][1024][192] fp32 -> Wt' [3072][1024] bf16, out-major,
// rows permuted into sections: c' = (e/64)*1024 + h*64 + (e%64)
// ---------------------------------------------------------------------------
__global__ __launch_bounds__(256) void prep_wkqv(
    const float* __restrict__ Wk, unsigned short* __restrict__ Wt)
{
    __shared__ float tile[32][33];
    const int h = blockIdx.z;
    const int k0 = blockIdx.x * 32, e0 = blockIdx.y * 32;
    const float* inh = Wk + (size_t)h * 1024 * 192;
    const int tx = threadIdx.x & 31, ty = threadIdx.x >> 5;
    #pragma unroll
    for (int i = 0; i < 4; i++)
        tile[ty + i * 8][tx] = inh[(size_t)(k0 + ty + i * 8) * 192 + e0 + tx];
    __syncthreads();
    #pragma unroll
    for (int i = 0; i < 4; i++) {
        int e = e0 + ty + i * 8;
        int cp = (e >> 6) * 1024 + h * 64 + (e & 63);
        Wt[(size_t)cp * 1024 + k0 + tx] = f2b(tile[tx][ty + i * 8]);
    }
}

// ---------------------------------------------------------------------------
// Pre-pass: tiled transpose, in fp32 [R][C] -> out bf16 [C][R] (for W_proj)
// ---------------------------------------------------------------------------
__global__ __launch_bounds__(256) void transpose_w(
    const float* __restrict__ in, unsigned short* __restrict__ outp, int R, int C)
{
    __shared__ float tile[32][33];
    const int r0 = blockIdx.x * 32, c0 = blockIdx.y * 32;
    const int tx = threadIdx.x & 31, ty = threadIdx.x >> 5;
    #pragma unroll
    for (int i = 0; i < 4; i++)
        tile[ty + i * 8][tx] = in[(size_t)(r0 + ty + i * 8) * C + c0 + tx];
    __syncthreads();
    #pragma unroll
    for (int i = 0; i < 4; i++)
        outp[(size_t)(c0 + ty + i * 8) * R + r0 + tx] = f2b(tile[tx][ty + i * 8]);
}

// ---------------------------------------------------------------------------
// Kernel: KQV projection as bf16 MFMA GEMM (unchanged from round 5).
// ---------------------------------------------------------------------------
__global__ __launch_bounds__(256) void gemm_kqv(
    const unsigned short* __restrict__ A,    // x16 [8192][1024]
    const unsigned short* __restrict__ Bt,   // Wt' [3072][1024] permuted
    const float* __restrict__ bk,            // [16][192] original bias
    unsigned short* __restrict__ Kb16,
    unsigned short* __restrict__ Qb16,
    unsigned short* __restrict__ Vt16)
{
    __shared__ unsigned short smem[16384];   // 32KB: As|Bs, reused as C-stage
    unsigned short* As = smem;               // [128][64]
    unsigned short* Bs = smem + 8192;        // [128][64]

    const int mt = blockIdx.x;               // 0..63
    const int ct = blockIdx.y;               // 0..23
    const int t = threadIdx.x;
    const int wave = t >> 6, lane = t & 63;
    const int lr = lane & 15, quad = lane >> 4;
    const int wm = wave >> 1, wn = wave & 1;
    const int row0 = mt * 128, col0 = ct * 128;
    const int sr = lane >> 3, sc = lane & 7;

    floatx4 acc[4][4];
    #pragma unroll
    for (int a = 0; a < 4; a++)
        #pragma unroll
        for (int n = 0; n < 4; n++) acc[a][n] = (floatx4){0.f, 0.f, 0.f, 0.f};

    for (int k0 = 0; k0 < 1024; k0 += 64) {
        __syncthreads();
        #pragma unroll
        for (int i = 0; i < 4; i++) {
            int q = wave + i * 4;            // 1KB chunk = 8 rows of 64
            GLDS16(A  + (size_t)(row0 + q * 8 + sr) * 1024 + k0 + sc * 8, As + q * 512);
            GLDS16(Bt + (size_t)(col0 + q * 8 + sr) * 1024 + k0 + sc * 8, Bs + q * 512);
        }
        __syncthreads();
        #pragma unroll
        for (int kc = 0; kc < 2; kc++) {
            short8 af[4], bf[4];
            #pragma unroll
            for (int i = 0; i < 4; i++) {
                af[i] = *(const short8*)(As + (wm * 64 + i * 16 + lr) * 64 + kc * 32 + quad * 8);
                bf[i] = *(const short8*)(Bs + (wn * 64 + i * 16 + lr) * 64 + kc * 32 + quad * 8);
            }
            #pragma unroll
            for (int a = 0; a < 4; a++)
                #pragma unroll
                for (int n = 0; n < 4; n++)
                    acc[a][n] = __builtin_amdgcn_mfma_f32_16x16x32_bf16(af[a], bf[n], acc[a][n], 0, 0, 0);
        }
    }

    // ---- epilogue ----
    const int sec = ct >> 3;                 // 0=K, 1=Q, 2=V (block-uniform)
    float bias[4];
    #pragma unroll
    for (int n = 0; n < 4; n++) {
        int c = col0 + wn * 64 + n * 16 + lr;
        int h = (c & 1023) >> 6;
        int e = sec * 64 + (c & 63);
        bias[n] = bk[h * 192 + e];
    }
    const int b = row0 >> 11;
    const int n0 = row0 & 2047;
    const float scl = (sec == 1) ? (0.125f * 1.44269504089f) : 1.0f;

    __syncthreads();                          // K-loop LDS reads complete
    if (sec < 2) {
        #pragma unroll
        for (int a = 0; a < 4; a++)
            #pragma unroll
            for (int n = 0; n < 4; n++) {
                int colS = (wn * 64 + n * 16 + lr) ^ (quad << 4);
                #pragma unroll
                for (int r = 0; r < 4; r++) {
                    int rw = wm * 64 + a * 16 + quad * 4 + r;
                    smem[rw * 128 + colS] = f2b((acc[a][n][r] + bias[n]) * scl);
                }
            }
        __syncthreads();
        unsigned short* dstbuf = (sec == 0) ? Kb16 : Qb16;
        const int rw = t >> 1, half = t & 1;
        const int h2 = (ct & 7) * 2 + half;
        const int s = (rw >> 2) & 3;
        unsigned short* dst = dstbuf + ((size_t)(b * 16 + h2) * 2048 + n0 + rw) * 64;
        #pragma unroll
        for (int u = 0; u < 8; u++) {
            int cg = half * 64 + ((u * 8) ^ (s << 4));
            *(float4*)(dst + u * 8) = *(const float4*)(&smem[rw * 128 + cg]);
        }
    } else {
        #pragma unroll
        for (int a = 0; a < 4; a++)
            #pragma unroll
            for (int n = 0; n < 4; n++) {
                int colv = wn * 64 + n * 16 + lr;
                int rowb = (wm * 64 + a * 16 + quad * 4) ^ ((colv & 7) << 3);
                ushort4 pk;
                pk.x = f2b(acc[a][n][0] + bias[n]);
                pk.y = f2b(acc[a][n][1] + bias[n]);
                pk.z = f2b(acc[a][n][2] + bias[n]);
                pk.w = f2b(acc[a][n][3] + bias[n]);
                *(ushort4*)(&smem[colv * 128 + rowb]) = pk;
            }
        __syncthreads();
        const int cg = t >> 1, hf = t & 1;
        const int d = cg & 63, h2 = (ct & 7) * 2 + (cg >> 6);
        unsigned short* dst = Vt16 + ((size_t)(b * 16 + h2) * 64 + d) * 2048 + n0 + hf * 64;
        #pragma unroll
        for (int u = 0; u < 8; u++) {
            int rr = hf * 64 + u * 8;
            int rs = rr ^ ((cg & 7) << 3);
            *(float4*)(dst + u * 8) = *(const float4*)(&smem[cg * 128 + rs]);
        }
    }
}

// ---------------------------------------------------------------------------
// Kernel: flash-style causal attention, 32x32x16 bf16 MFMA, S^T trick.
// Block: 64-row Q-tiles paired {bx, 31-bx} (33 works). 4 waves = 2x2
// (w_q = qrow half, w_k = kcol half), each computes one 32x32 S^T tile:
//   S^T = mfma(A=K, B=Q)  ->  C layout: qrow = lane&31, kcols in-register.
// P then feeds PV's A operand after a PURE in-lane repack (k-order of PV is
// permuted identically on the V side via b64 LDS reads), so the P matrix
// never touches LDS and softmax needs no per-iteration cross-lane ops.
// O halves (w_k=0/1) summed once in an LDS epilogue.
// ---------------------------------------------------------------------------
__global__ __launch_bounds__(256, 3) void attn_mfma(
    const unsigned short* __restrict__ Kb,   // [bh][2048][64]
    const unsigned short* __restrict__ Qb,   // [bh][2048][64], pre-scaled
    const unsigned short* __restrict__ Vt,   // [bh][64][2048]
    unsigned short* __restrict__ sa)         // [8192][1024] bf16
{
    const int bx = blockIdx.x;               // 0..15
    const int bh = blockIdx.y;
    const int b = bh >> 4, h = bh & 15;
    const int wave = threadIdx.x >> 6;
    const int lane = threadIdx.x & 63;
    const int ln31 = lane & 31;
    const int hi = lane >> 5;
    const int w_q = wave >> 1, w_k = wave & 1;
    const int qt_[2] = {bx, 31 - bx};

    __shared__ unsigned short smem[8192];    // Ks[4096] | Vs[4096]; reused as Obuf
    __shared__ float lsbuf[2][2][64];
    __shared__ float invbuf[2][64];
    unsigned short* Ks = smem;
    unsigned short* Vs = smem + 4096;

    const unsigned short* Kbh = Kb + (size_t)bh * 2048 * 64;
    const unsigned short* Vbh = Vt + (size_t)bh * 64 * 2048;
    const unsigned short* Qbh = Qb + (size_t)bh * 2048 * 64;

    // Q B-fragments: n = ln31 -> qrow, k = ch*16 + hi*8 + j
    short8 qf[2][4];
    #pragma unroll
    for (int tt = 0; tt < 2; tt++)
        #pragma unroll
        for (int ch = 0; ch < 4; ch++)
            qf[tt][ch] = *(const short8*)(Qbh +
                (size_t)(qt_[tt] * 64 + w_q * 32 + ln31) * 64 + ch * 16 + hi * 8);

    floatx16 O[2][2];
    #pragma unroll
    for (int tt = 0; tt < 2; tt++)
        #pragma unroll
        for (int d32 = 0; d32 < 2; d32++)
            #pragma unroll
            for (int r = 0; r < 16; r++) O[tt][d32][r] = 0.f;
    float ls[2] = {0.f, 0.f};

    const int r_local = lane >> 3, cc = lane & 7;
    const int swz = cc ^ r_local;            // data chunk this lane stages

    for (int kt = 0; kt <= qt_[1]; kt++) {
        const int k0 = kt * 64;
        __syncthreads();                      // prior iteration's LDS reads done
        #pragma unroll
        for (int j = 0; j < 2; j++) {
            int R = wave * 16 + j * 8 + r_local;
            GLDS16(Kbh + (size_t)(k0 + R) * 64 + swz * 8, Ks + (wave * 16 + j * 8) * 64 + lane * 8);
            GLDS16(Vbh + (size_t)R * 2048 + k0 + swz * 8, Vs + (wave * 16 + j * 8) * 64 + lane * 8);
        }
        __syncthreads();                      // GLDS drained + all waves

        #pragma unroll
        for (int tt = 0; tt < 2; tt++) {
            const int qt = qt_[tt];
            if (kt > qt) continue;
            const bool diag = (kt == qt);
            if (diag && w_k > w_q) continue;  // fully-masked quadrant

            // S^T = K . Q^T  (A=K: m=kcol; B=Q: n=qrow)
            floatx16 S;
            #pragma unroll
            for (int r = 0; r < 16; r++) S[r] = 0.f;
            #pragma unroll
            for (int ch = 0; ch < 4; ch++) {
                int R = w_k * 32 + ln31;
                short8 kf = *(const short8*)(Ks + R * 64 + (((2 * ch + hi) ^ (R & 7)) * 8));
                S = __builtin_amdgcn_mfma_f32_32x32x16_bf16(kf, qf[tt][ch], S, 0, 0, 0);
            }

            // causal mask (diagonal 32x32 quadrant only): kcol rr vs qrow ln31
            if (diag && w_k == w_q) {
                #pragma unroll
                for (int reg = 0; reg < 16; reg++) {
                    int rr = (reg & 3) + 8 * (reg >> 2) + 4 * hi;
                    if (rr > ln31) S[reg] = -INFINITY;
                }
            }

            // P = 2^s, per-lane row-sum, in-lane bf16 pair packing
            float p[16];
            float psum = 0.f;
            #pragma unroll
            for (int reg = 0; reg < 16; reg++) {
                p[reg] = __builtin_amdgcn_exp2f(S[reg]);
                psum += p[reg];
            }
            ls[tt] += psum;
            unsigned pk[4][2];
            #pragma unroll
            for (int g = 0; g < 4; g++) {
                pk[g][0] = (unsigned)f2b_fast(p[4 * g + 0]) | ((unsigned)f2b_fast(p[4 * g + 1]) << 16);
                pk[g][1] = (unsigned)f2b_fast(p[4 * g + 2]) | ((unsigned)f2b_fast(p[4 * g + 3]) << 16);
            }

            // O += P V with permuted k-order: k(hi,j) = 8*(2c+(j>>2)) + 4hi + (j&3)
            #pragma unroll
            for (int c16 = 0; c16 < 2; c16++) {
                Frag8 ua;
                ua.i = make_int4((int)pk[2 * c16][0], (int)pk[2 * c16][1],
                                 (int)pk[2 * c16 + 1][0], (int)pk[2 * c16 + 1][1]);
                const int dcA = w_k * 4 + 2 * c16;
                #pragma unroll
                for (int d32 = 0; d32 < 2; d32++) {
                    int R2 = d32 * 32 + ln31;
                    int rb = R2 * 64;
                    uint2 u0 = *(const uint2*)(Vs + rb + ((dcA ^ (R2 & 7)) * 8) + 4 * hi);
                    uint2 u1 = *(const uint2*)(Vs + rb + (((dcA + 1) ^ (R2 & 7)) * 8) + 4 * hi);
                    Frag8 uv;
                    uv.i = make_int4((int)u0.x, (int)u0.y, (int)u1.x, (int)u1.y);
                    O[tt][d32] = __builtin_amdgcn_mfma_f32_32x32x16_bf16(ua.s, uv.s, O[tt][d32], 0, 0, 0);
                }
            }
        }
    }

    // ---- epilogue: combine w_k halves, normalize, store ----
    ls[0] += __shfl_xor(ls[0], 32);
    ls[1] += __shfl_xor(ls[1], 32);
    __syncthreads();                          // Ks/Vs reads finished everywhere
    if (hi == 0) {
        lsbuf[0][w_k][w_q * 32 + ln31] = ls[0];
        lsbuf[1][w_k][w_q * 32 + ln31] = ls[1];
    }
    float* Obuf = (float*)smem;               // [64][64] fp32 = 16KB

    #pragma unroll
    for (int tt = 0; tt < 2; tt++) {
        if (w_k == 0) {
            #pragma unroll
            for (int d32 = 0; d32 < 2; d32++)
                #pragma unroll
                for (int reg = 0; reg < 16; reg++) {
                    int rr = (reg & 3) + 8 * (reg >> 2) + 4 * hi;
                    Obuf[(w_q * 32 + rr) * 64 + d32 * 32 + ln31] = O[tt][d32][reg];
                }
        }
        __syncthreads();
        if (tt == 0 && threadIdx.x < 128) {
            int ttt = threadIdx.x >> 6, row = threadIdx.x & 63;
            invbuf[ttt][row] = 1.0f / (lsbuf[ttt][0][row] + lsbuf[ttt][1][row]);
        }
        if (tt == 0) __syncthreads();         // invbuf ready before first use
        if (w_k == 1) {
            #pragma unroll
            for (int d32 = 0; d32 < 2; d32++)
                #pragma unroll
                for (int reg = 0; reg < 16; reg++) {
                    int rr = (reg & 3) + 8 * (reg >> 2) + 4 * hi;
                    int row = w_q * 32 + rr;
                    float v = (Obuf[row * 64 + d32 * 32 + ln31] + O[tt][d32][reg]) * invbuf[tt][row];
                    sa[((size_t)(b * 2048 + qt_[tt] * 64 + row)) * 1024 + h * 64 + d32 * 32 + ln31] = f2b(v);
                }
        }
        __syncthreads();                      // Obuf free for next tt
    }
}

// ---------------------------------------------------------------------------
// Kernel: output projection as bf16 MFMA GEMM, fp32 out.
// ---------------------------------------------------------------------------
__global__ __launch_bounds__(256) void gemm_proj(
    const unsigned short* __restrict__ A,    // sa16 [8192][1024]
    const unsigned short* __restrict__ Bt,   // Wpt [1024][1024] out-major
    const float* __restrict__ bp,            // [1024]
    float* __restrict__ out)                 // [8192][1024] fp32
{
    __shared__ unsigned short smem[16384];
    unsigned short* As = smem;
    unsigned short* Bs = smem + 8192;

    const int mt = blockIdx.x;               // 0..63
    const int ct = blockIdx.y;               // 0..7
    const int t = threadIdx.x;
    const int wave = t >> 6, lane = t & 63;
    const int lr = lane & 15, quad = lane >> 4;
    const int wm = wave >> 1, wn = wave & 1;
    const int row0 = mt * 128, col0 = ct * 128;
    const int sr = lane >> 3, sc = lane & 7;

    floatx4 acc[4][4];
    #pragma unroll
    for (int a = 0; a < 4; a++)
        #pragma unroll
        for (int n = 0; n < 4; n++) acc[a][n] = (floatx4){0.f, 0.f, 0.f, 0.f};

    for (int k0 = 0; k0 < 1024; k0 += 64) {
        __syncthreads();
        #pragma unroll
        for (int i = 0; i < 4; i++) {
            int q = wave + i * 4;
            GLDS16(A  + (size_t)(row0 + q * 8 + sr) * 1024 + k0 + sc * 8, As + q * 512);
            GLDS16(Bt + (size_t)(col0 + q * 8 + sr) * 1024 + k0 + sc * 8, Bs + q * 512);
        }
        __syncthreads();
        #pragma unroll
        for (int kc = 0; kc < 2; kc++) {
            short8 af[4], bf[4];
            #pragma unroll
            for (int i = 0; i < 4; i++) {
                af[i] = *(const short8*)(As + (wm * 64 + i * 16 + lr) * 64 + kc * 32 + quad * 8);
                bf[i] = *(const short8*)(Bs + (wn * 64 + i * 16 + lr) * 64 + kc * 32 + quad * 8);
            }
            #pragma unroll
            for (int a = 0; a < 4; a++)
                #pragma unroll
                for (int n = 0; n < 4; n++)
                    acc[a][n] = __builtin_amdgcn_mfma_f32_16x16x32_bf16(af[a], bf[n], acc[a][n], 0, 0, 0);
        }
    }

    float bias[4]; int cols[4];
    #pragma unroll
    for (int n = 0; n < 4; n++) {
        cols[n] = col0 + wn * 64 + n * 16 + lr;
        bias[n] = bp[cols[n]];
    }
    #pragma unroll
    for (int a = 0; a < 4; a++) {
        #pragma unroll
        for (int n = 0; n < 4; n++) {
            #pragma unroll
            for (int r = 0; r < 4; r++) {
                int m = row0 + wm * 64 + a * 16 + quad * 4 + r;
                out[(size_t)m * 1024 + cols[n]] = acc[a][n][r] + bias[n];
            }
        }
    }
}

extern "C" void kernel_launch(void* const* d_in, const int* in_sizes, int n_in,
                              void* d_out, int out_size, void* d_ws, size_t ws_size,
                              hipStream_t stream) {
    const float* x  = (const float*)d_in[0];   // [4,2048,1024]
    const float* Wk = (const float*)d_in[1];   // [16,1024,192]
    const float* bk = (const float*)d_in[2];   // [16,192]
    const float* Wp = (const float*)d_in[3];   // [1024,1024]
    const float* bp = (const float*)d_in[4];   // [1024]
    float* out = (float*)d_out;                // [4,2048,1024]

    unsigned short* Kb16 = (unsigned short*)d_ws;   // [bh][2048][64]
    unsigned short* Qb16 = Kb16 + NKV;              // pre-scaled by 0.125*log2e
    unsigned short* Vt16 = Qb16 + NKV;              // [bh][64][2048]
    unsigned short* sa16 = Vt16 + NKV;              // [8192][1024]
    unsigned short* x16  = sa16 + 8388608ull;       // [8192][1024]
    unsigned short* Wt   = x16  + 8388608ull;       // [3072][1024] permuted
    unsigned short* Wpt  = Wt   + 3145728ull;       // [1024][1024]

    convert_x<<<4096, 256, 0, stream>>>(x, x16);
    prep_wkqv<<<dim3(32, 6, 16), 256, 0, stream>>>(Wk, Wt);
    transpose_w<<<dim3(32, 32, 1), 256, 0, stream>>>(Wp, Wpt, 1024, 1024);
    gemm_kqv<<<dim3(64, 24), 256, 0, stream>>>(x16, Wt, bk, Kb16, Qb16, Vt16);
    attn_mfma<<<dim3(16, 64), 256, 0, stream>>>(Kb16, Qb16, Vt16, sa16);
    gemm_proj<<<dim3(64, 8), 256, 0, stream>>>(sa16, Wpt, bp, out);
}